// Round 1
// baseline (1564.995 us; speedup 1.0000x reference)
//
#include <hip/hip_runtime.h>

#define N 192
#define DT 0.01f
#define NT 10  // fixed by setup_inputs()

// d(dc*g)[p] along one axis, np.gradient semantics (central interior,
// one-sided at edges) applied twice. xi/di: linear center indices into
// x / dc; sx/sd: element strides along this axis; p: position; n: length.
__device__ __forceinline__ float axis_term(const float* __restrict__ x,
                                           const float* __restrict__ dc,
                                           int xi, int di, int p, int n,
                                           int sx, int sd) {
  // gradient of x at absolute position q (|q-p| <= 1)
  auto g = [&](int q) -> float {
    int dq = q - p;
    if (q == 0)     return x[xi + (dq + 1) * sx] - x[xi + dq * sx];
    if (q == n - 1) return x[xi + dq * sx]       - x[xi + (dq - 1) * sx];
    return 0.5f * (x[xi + (dq + 1) * sx] - x[xi + (dq - 1) * sx]);
  };
  auto F = [&](int q) -> float { return dc[di + (q - p) * sd] * g(q); };
  if (p == 0)     return F(1)     - F(0);
  if (p == n - 1) return F(n - 1) - F(n - 2);
  return 0.5f * (F(p + 1) - F(p - 1));
}

__global__ __launch_bounds__(N) void diffuse_step(const float* __restrict__ xin,
                                                  const float* __restrict__ dc,
                                                  float* __restrict__ xout) {
  const int k = threadIdx.x;         // c axis
  const int j = blockIdx.x % N;      // r axis
  const int i = blockIdx.x / N;      // s axis
  const int di = (i * N + j) * N + k;      // dc linear index
  const int xbase = di * 3;                // X linear index, channel 0

  const int SX_S = 3 * N * N, SD_S = N * N;
  const int SX_R = 3 * N,     SD_R = N;
  const int SX_C = 3,         SD_C = 1;

#pragma unroll
  for (int a = 0; a < 3; ++a) {
    const int xi = xbase + a;
    float delta = axis_term(xin, dc, xi, di, i, N, SX_S, SD_S)
                + axis_term(xin, dc, xi, di, j, N, SX_R, SD_R)
                + axis_term(xin, dc, xi, di, k, N, SX_C, SD_C);
    xout[xi] = xin[xi] + DT * delta;
  }
}

extern "C" void kernel_launch(void* const* d_in, const int* in_sizes, int n_in,
                              void* d_out, int out_size, void* d_ws, size_t ws_size,
                              hipStream_t stream) {
  const float* X  = (const float*)d_in[0];
  const float* dc = (const float*)d_in[1];
  float* out = (float*)d_out;

  const size_t need = (size_t)out_size * sizeof(float);
  dim3 grid(N * N), block(N);

  if (ws_size >= need) {
    // ping-pong: in -> ws -> out -> ws -> ... -> out  (NT even ends in out)
    float* ws = (float*)d_ws;
    const float* src = X;
    for (int t = 0; t < NT; ++t) {
      float* dst = (t % 2 == 0) ? ws : out;
      diffuse_step<<<grid, block, 0, stream>>>(src, dc, dst);
      src = dst;
    }
  } else {
    // fallback: use d_in[0] as scratch (harness restores it before every
    // timed launch). in -> out -> in -> out -> ... ; NT even would end in
    // d_in, so do first step to out, then alternate, final copy if needed.
    float* xmut = (float*)d_in[0];
    const float* src = X;
    float* last = nullptr;
    for (int t = 0; t < NT; ++t) {
      float* dst = (t % 2 == 0) ? out : xmut;
      diffuse_step<<<grid, block, 0, stream>>>(src, dc, dst);
      src = dst;
      last = dst;
    }
    if (last != out) {
      hipMemcpyAsync(out, last, need, hipMemcpyDeviceToDevice, stream);
    }
  }
}

// Round 2
// 1524.084 us; speedup vs baseline: 1.0268x; 1.0268x over previous
//
#include <hip/hip_runtime.h>

#define N 192
#define ROWF (N * 3)   // floats per (i,j) row of X
#define DT 0.01f
#define NT 10          // fixed by setup_inputs()

// d(dc*g)/dp at p along one axis, np.gradient semantics applied twice.
// x(q), d(q) are accessors along the axis; q always stays in [0, n-1].
template <class XF, class DF>
__device__ __forceinline__ float axis_term(XF&& x, DF&& d, int p, int n) {
  auto g = [&](int q) -> float {
    if (q == 0)     return x(1) - x(0);
    if (q == n - 1) return x(n - 1) - x(n - 2);
    return 0.5f * (x(q + 1) - x(q - 1));
  };
  auto F = [&](int q) -> float { return d(q) * g(q); };
  if (p == 0)     return F(1) - F(0);
  if (p == n - 1) return F(n - 1) - F(n - 2);
  return 0.5f * (F(p + 1) - F(p - 1));
}

__global__ __launch_bounds__(N) void diffuse_step(const float* __restrict__ xin,
                                                  const float* __restrict__ dc,
                                                  float* __restrict__ xout) {
  __shared__ float sx[ROWF];  // center row of X (192 voxels x 3 ch)
  __shared__ float sd[N];     // center row of dc
  __shared__ float so[ROWF];  // staged output row

  const int t = threadIdx.x;

  // XCD-aware swizzle: HW assigns blockIdx round-robin to the 8 XCDs, so give
  // XCD x the contiguous logical range [x*Q, (x+1)*Q) -> each XCD owns a
  // 24-plane s-slab; s+-2 / r+-2 neighbors then hit its private 4 MB L2.
  const int NW = N * N, Q = NW / 8;           // 36864 % 8 == 0 -> bijective
  const int lb = (blockIdx.x % 8) * Q + blockIdx.x / 8;
  const int j = lb % N;
  const int i = lb / N;

  const size_t rowoff = (size_t)(i * N + j);
  const float* xrow = xin + rowoff * ROWF;
  const float* drow = dc + rowoff * N;

  // Stage center rows as aligned float4 (row bases are 16B-aligned).
  if (t < 144) ((float4*)sx)[t] = ((const float4*)xrow)[t];
  else         ((float4*)sd)[t - 144] = ((const float4*)drow)[t - 144];
  __syncthreads();

  const int k = t;

#pragma unroll
  for (int a = 0; a < 3; ++a) {
    // c axis: entirely from LDS
    float delta = axis_term(
        [&](int q) { return sx[q * 3 + a]; },
        [&](int q) { return sd[q]; }, k, N);
    // r axis: rows i, q, k (q = j-2..j+2 as needed)
    delta += axis_term(
        [&](int q) { return xin[((size_t)(i * N + q) * N + k) * 3 + a]; },
        [&](int q) { return dc[(size_t)(i * N + q) * N + k]; }, j, N);
    // s axis: planes q
    delta += axis_term(
        [&](int q) { return xin[((size_t)(q * N + j) * N + k) * 3 + a]; },
        [&](int q) { return dc[(size_t)(q * N + j) * N + k]; }, i, N);

    so[k * 3 + a] = sx[k * 3 + a] + DT * delta;
  }

  __syncthreads();
  // Coalesced full-line writeback: 144 aligned float4 = 18 x 128B lines.
  float* orow = xout + rowoff * ROWF;
  if (t < 144) ((float4*)orow)[t] = ((const float4*)so)[t];
}

extern "C" void kernel_launch(void* const* d_in, const int* in_sizes, int n_in,
                              void* d_out, int out_size, void* d_ws, size_t ws_size,
                              hipStream_t stream) {
  const float* X  = (const float*)d_in[0];
  const float* dc = (const float*)d_in[1];
  float* out = (float*)d_out;

  const size_t need = (size_t)out_size * sizeof(float);
  dim3 grid(N * N), block(N);

  if (ws_size >= need) {
    // ping-pong: in -> ws -> out -> ws -> ... -> out (NT even ends in out)
    float* ws = (float*)d_ws;
    const float* src = X;
    for (int t = 0; t < NT; ++t) {
      float* dst = (t % 2 == 0) ? ws : out;
      diffuse_step<<<grid, block, 0, stream>>>(src, dc, dst);
      src = dst;
    }
  } else {
    float* xmut = (float*)d_in[0];
    const float* src = X;
    float* last = nullptr;
    for (int t = 0; t < NT; ++t) {
      float* dst = (t % 2 == 0) ? out : xmut;
      diffuse_step<<<grid, block, 0, stream>>>(src, dc, dst);
      src = dst;
      last = dst;
    }
    if (last != out) {
      hipMemcpyAsync(out, last, need, hipMemcpyDeviceToDevice, stream);
    }
  }
}

// Round 3
// 1492.260 us; speedup vs baseline: 1.0487x; 1.0213x over previous
//
#include <hip/hip_runtime.h>

#define N 192
#define ROWF (N * 3)   // floats per (i,j) row of X
#define DT 0.01f
#define NT 10          // fixed by setup_inputs()

__device__ __forceinline__ int clampN(int v) { return min(max(v, 0), N - 1); }

// d(dc*g)/dp at p along one axis, np.gradient semantics applied twice.
// x(q), d(q) accessors; evaluated q always stays within [p-2, p+2] & [0, n-1].
template <class XF, class DF>
__device__ __forceinline__ float axis_term(XF&& x, DF&& d, int p, int n) {
  auto g = [&](int q) -> float {
    if (q == 0)     return x(1) - x(0);
    if (q == n - 1) return x(n - 1) - x(n - 2);
    return 0.5f * (x(q + 1) - x(q - 1));
  };
  auto F = [&](int q) -> float { return d(q) * g(q); };
  if (p == 0)     return F(1) - F(0);
  if (p == n - 1) return F(n - 1) - F(n - 2);
  return 0.5f * (F(p + 1) - F(p - 1));
}

// One block = one (i,j) output row along c. ALL stencil data staged to LDS:
//   sx[0..4]  = in-plane X rows (i, j-2..j+2)
//   sx[5..8]  = s-neighbor X rows (i-2, i-1, i+1, i+2) at row j
//   sd[0..4]  = dc rows: (i,j), (i,j-1), (i,j+1), (i-1,j), (i+1,j)
// Staging = 1536 float4 = 8 per thread, all contiguous aligned rows.
__global__ __launch_bounds__(N) void diffuse_step(const float* __restrict__ xin,
                                                  const float* __restrict__ dc,
                                                  float* __restrict__ xout) {
  __shared__ float sx[9][ROWF];
  __shared__ float sd[5][N];
  __shared__ float so[ROWF];

  const int t = threadIdx.x;

  // XCD-aware swizzle: each XCD owns a contiguous 24-plane s-slab so the
  // i+-2 / j+-2 row reuse hits its private 4 MB L2.
  const int NW = N * N, Q = NW / 8;          // 36864 % 8 == 0 -> bijective
  const int lb = (blockIdx.x % 8) * Q + blockIdx.x / 8;
  const int j = lb % N;
  const int i = lb / N;

  // ---- stage 14 rows (9 X + 5 dc) as 1536 float4, 8 per thread ----
#pragma unroll
  for (int u = 0; u < 8; ++u) {
    const int f = t + N * u;
    if (f < 9 * 144) {                 // X region: row r, float4 offset off
      const int r = f / 144;
      const int off = f - r * 144;
      int ii, jj;
      if (r < 5) { ii = i; jj = clampN(j - 2 + r); }
      else       { ii = clampN(i + ((r < 7) ? r - 7 : r - 6)); jj = j; }
      ((float4*)sx)[f] =
          ((const float4*)xin)[(size_t)(ii * N + jj) * 144 + off];
    } else {                           // dc region
      const int f2 = f - 9 * 144;
      const int r = f2 / 48;
      const int off = f2 - r * 48;
      int ii = i, jj = j;
      if      (r == 1) jj = clampN(j - 1);
      else if (r == 2) jj = clampN(j + 1);
      else if (r == 3) ii = clampN(i - 1);
      else if (r == 4) ii = clampN(i + 1);
      ((float4*)sd)[f2] =
          ((const float4*)dc)[(size_t)(ii * N + jj) * 48 + off];
    }
  }
  __syncthreads();

  const int k = t;

#pragma unroll
  for (int a = 0; a < 3; ++a) {
    // c axis: center row, per-lane position k
    float delta = axis_term(
        [&](int q) { return sx[2][q * 3 + a]; },
        [&](int q) { return sd[0][q]; }, k, N);
    // r axis: rows j-2..j+2 -> sx[0..4]; dc(j-1/j/j+1) -> sd[1]/sd[0]/sd[2]
    delta += axis_term(
        [&](int q) { return sx[q - j + 2][k * 3 + a]; },
        [&](int q) { int dq = q - j;
                     return sd[dq == 0 ? 0 : (dq < 0 ? 1 : 2)][k]; }, j, N);
    // s axis: i-2,-1,+1,+2 -> sx[5,6,7,8]; center -> sx[2];
    //         dc(i-1/i/i+1) -> sd[3]/sd[0]/sd[4]
    delta += axis_term(
        [&](int q) { int dq = q - i;
                     return sx[dq == 0 ? 2 : (dq < 0 ? dq + 7 : dq + 6)][k * 3 + a]; },
        [&](int q) { int dq = q - i;
                     return sd[dq == 0 ? 0 : (dq < 0 ? 3 : 4)][k]; }, i, N);

    so[k * 3 + a] = sx[2][k * 3 + a] + DT * delta;
  }

  __syncthreads();
  // Coalesced full-line writeback: 144 aligned float4 = 18 x 128B lines.
  float* orow = xout + (size_t)(i * N + j) * ROWF;
  if (t < 144) ((float4*)orow)[t] = ((const float4*)so)[t];
}

extern "C" void kernel_launch(void* const* d_in, const int* in_sizes, int n_in,
                              void* d_out, int out_size, void* d_ws, size_t ws_size,
                              hipStream_t stream) {
  const float* X  = (const float*)d_in[0];
  const float* dc = (const float*)d_in[1];
  float* out = (float*)d_out;

  const size_t need = (size_t)out_size * sizeof(float);
  dim3 grid(N * N), block(N);

  if (ws_size >= need) {
    // ping-pong: in -> ws -> out -> ws -> ... -> out (NT even ends in out)
    float* ws = (float*)d_ws;
    const float* src = X;
    for (int t = 0; t < NT; ++t) {
      float* dst = (t % 2 == 0) ? ws : out;
      diffuse_step<<<grid, block, 0, stream>>>(src, dc, dst);
      src = dst;
    }
  } else {
    float* xmut = (float*)d_in[0];
    const float* src = X;
    float* last = nullptr;
    for (int t = 0; t < NT; ++t) {
      float* dst = (t % 2 == 0) ? out : xmut;
      diffuse_step<<<grid, block, 0, stream>>>(src, dc, dst);
      src = dst;
      last = dst;
    }
    if (last != out) {
      hipMemcpyAsync(out, last, need, hipMemcpyDeviceToDevice, stream);
    }
  }
}

// Round 5
// 1118.581 us; speedup vs baseline: 1.3991x; 1.3341x over previous
//
#include <hip/hip_runtime.h>

#define N 192
#define ROWF (N * 3)   // floats per (i,j) row of X
#define DT 0.01f
#define NT 10          // fixed by setup_inputs()

__device__ __forceinline__ int clampN(int v) { return min(max(v, 0), N - 1); }

struct f3 { float x, y, z; };
__device__ __forceinline__ f3 operator-(f3 a, f3 b) { return {a.x - b.x, a.y - b.y, a.z - b.z}; }
__device__ __forceinline__ f3 operator+(f3 a, f3 b) { return {a.x + b.x, a.y + b.y, a.z + b.z}; }
__device__ __forceinline__ f3 operator*(float s, f3 a) { return {s * a.x, s * a.y, s * a.z}; }

// d(dc*g)/dp at p along one axis, np.gradient applied twice; all 3 channels.
template <class XF, class DF>
__device__ __forceinline__ f3 axis_term3(XF&& x, DF&& d, int p, int n) {
  auto g = [&](int q) -> f3 {
    if (q == 0)     return x(1) - x(0);
    if (q == n - 1) return x(n - 1) - x(n - 2);
    return 0.5f * (x(q + 1) - x(q - 1));
  };
  auto F = [&](int q) -> f3 { return d(q) * g(q); };
  if (p == 0)     return F(1) - F(0);
  if (p == n - 1) return F(n - 1) - F(n - 2);
  return 0.5f * (F(p + 1) - F(p - 1));
}

// One block = one (i,j) row along c. LDS rows:
//   sx[0..4] = in-plane X rows (i, j-2..j+2); sx[5..8] = (i-2,i-1,i+1,i+2) at j
//   sd[0..4] = dc rows (i,j), (i,j-1), (i,j+1), (i-1,j), (i+1,j)
// Interior blocks skip X rows {1,3,6,7}: the +-2-stride stencil only reads
// j+-1 / i+-1 X rows inside np.gradient's one-sided edge formulas.
__global__ __launch_bounds__(N) void diffuse_step(const float* __restrict__ xin,
                                                  const float* __restrict__ dc,
                                                  float* __restrict__ xout) {
  __shared__ float sx[9][ROWF];
  __shared__ float sd[5][N];
  __shared__ float so[ROWF];

  const int t = threadIdx.x;

  // XCD-aware swizzle: each XCD owns a contiguous 24-plane s-slab.
  const int NW = N * N, Q = NW / 8;          // 36864 % 8 == 0 -> bijective
  const int lb = (blockIdx.x % 8) * Q + blockIdx.x / 8;
  const int j = lb % N;
  const int i = lb / N;

  const bool jeog = (j < 2) || (j >= N - 2);
  const bool ieog = (i < 2) || (i >= N - 2);

  // ---- stage rows: lanes <144 do X rows (144 float4), lanes >=144 do dc ----
#pragma unroll
  for (int r = 0; r < 9; ++r) {
    const bool need = (r == 0 || r == 2 || r == 4 || r == 5 || r == 8) ||
                      ((r == 1 || r == 3) && jeog) ||
                      ((r == 6 || r == 7) && ieog);
    if (need && t < 144) {
      int ii, jj;
      if (r < 5) { ii = i; jj = clampN(j - 2 + r); }
      else       { ii = clampN(i + ((r < 7) ? r - 7 : r - 6)); jj = j; }
      ((float4*)(sx[r]))[t] = ((const float4*)xin)[(size_t)(ii * N + jj) * 144 + t];
    }
    if (r < 5 && t >= 144) {
      int ii = i, jj = j;
      if      (r == 1) jj = clampN(j - 1);
      else if (r == 2) jj = clampN(j + 1);
      else if (r == 3) ii = clampN(i - 1);
      else if (r == 4) ii = clampN(i + 1);
      ((float4*)(sd[r]))[t - 144] = ((const float4*)dc)[(size_t)(ii * N + jj) * 48 + (t - 144)];
    }
  }
  __syncthreads();

  const int k = t;

  auto ldx = [&](int row, int q) -> f3 {
    const float* p = &sx[row][q * 3];
    return f3{p[0], p[1], p[2]};
  };

  // c axis (per-lane p=k)
  f3 delta = axis_term3([&](int q) { return ldx(2, q); },
                        [&](int q) { return sd[0][q]; }, k, N);
  // r axis (uniform p=j): row q -> sx[q-j+2]; dc(j-1/j/j+1) -> sd[1]/sd[0]/sd[2]
  delta = delta + axis_term3(
      [&](int q) { return ldx(q - j + 2, k); },
      [&](int q) { int dq = q - j; return sd[dq == 0 ? 0 : (dq < 0 ? 1 : 2)][k]; },
      j, N);
  // s axis (uniform p=i): i-2,-1,+1,+2 -> sx[5,6,7,8]; center -> sx[2]
  delta = delta + axis_term3(
      [&](int q) { int dq = q - i;
                   return ldx(dq == 0 ? 2 : (dq < 0 ? dq + 7 : dq + 6), k); },
      [&](int q) { int dq = q - i;
                   return sd[dq == 0 ? 0 : (dq < 0 ? 3 : 4)][k]; },
      i, N);

  const f3 ctr = ldx(2, k);
  const f3 res = ctr + DT * delta;
  so[k * 3 + 0] = res.x;
  so[k * 3 + 1] = res.y;
  so[k * 3 + 2] = res.z;

  __syncthreads();
  // Coalesced full-line writeback: 144 aligned float4 = 18 x 128B lines.
  float* orow = xout + (size_t)(i * N + j) * ROWF;
  if (t < 144) ((float4*)orow)[t] = ((const float4*)so)[t];
}

extern "C" void kernel_launch(void* const* d_in, const int* in_sizes, int n_in,
                              void* d_out, int out_size, void* d_ws, size_t ws_size,
                              hipStream_t stream) {
  const float* X  = (const float*)d_in[0];
  const float* dc = (const float*)d_in[1];
  float* out = (float*)d_out;

  const size_t need = (size_t)out_size * sizeof(float);
  dim3 grid(N * N), block(N);

  if (ws_size >= need) {
    // ping-pong: in -> ws -> out -> ws -> ... -> out (NT even ends in out)
    float* ws = (float*)d_ws;
    const float* src = X;
    for (int t = 0; t < NT; ++t) {
      float* dst = (t % 2 == 0) ? ws : out;
      diffuse_step<<<grid, block, 0, stream>>>(src, dc, dst);
      src = dst;
    }
  } else {
    float* xmut = (float*)d_in[0];
    const float* src = X;
    float* last = nullptr;
    for (int t = 0; t < NT; ++t) {
      float* dst = (t % 2 == 0) ? out : xmut;
      diffuse_step<<<grid, block, 0, stream>>>(src, dc, dst);
      src = dst;
      last = dst;
    }
    if (last != out) {
      hipMemcpyAsync(out, last, need, hipMemcpyDeviceToDevice, stream);
    }
  }
}